// Round 1
// baseline (114.937 us; speedup 1.0000x reference)
//
#include <hip/hip_runtime.h>
#include <hip/hip_bf16.h>

// Problem: p[256][128][32][32] f32.
//   unit = p / ||p||_c ; wm = boxsum3x3(unit)/9 ; sim = sum_c unit*wm
//   out[b, c&1, h, w, c>>1] = p[b,c,h,w] * sim[b,h,w]   (shape [256,2,32,32,64] -> [256,2048,64])
//
// Fused single kernel: block = (image b, 4-row strip). Stage 6 rows (strip+halo)
// of raw p in LDS (pad 33 -> all phases bank-conflict-free), compute inv-norms,
// sim via 3x3 stencil of p*inv products, write coalesced output.

#define NTHR 512
#define PRAW_F (6 * 128 * 33)
#define PART_F (2 * 6 * 32)
#define INVN_F (6 * 32)
#define SPART_F (4 * 4 * 32)
#define SIMV_F (4 * 32)
#define LDS_FLOATS (PRAW_F + PART_F + INVN_F + SPART_F + SIMV_F)

__global__ __launch_bounds__(NTHR) void bcim_fused(const float* __restrict__ p,
                                                   float* __restrict__ out) {
    extern __shared__ float lds[];
    float* praw  = lds;                  // [6][128][33] raw p rows r0-1 .. r0+4
    float* part  = praw + PRAW_F;        // [2][6][32] norm partials
    float* invn  = part + PART_F;        // [6][32] 1/||p|| (0 for pad rows)
    float* spart = invn + INVN_F;        // [4][4][32] sim partials
    float* simv  = spart + SPART_F;      // [4][32] final sim

    const int tid = threadIdx.x;
    const int bid = blockIdx.x;
    const int b  = bid >> 3;
    const int sb = bid & 7;
    const int r0 = sb << 2;

    // ---------------- load 6 rows of p[b] (zero-fill out-of-image) ----------------
    const float* pb = p + (size_t)b * 131072;  // 128*32*32
    for (int idx = tid; idx < 6144; idx += NTHR) {  // 128 c * 6 ri * 8 wq
        const int c   = idx / 48;
        const int rem = idx - c * 48;
        const int ri  = rem >> 3;
        const int wq  = rem & 7;
        const int g   = r0 - 1 + ri;
        float4 v = make_float4(0.f, 0.f, 0.f, 0.f);
        if ((unsigned)g < 32u)
            v = *(const float4*)(pb + c * 1024 + g * 32 + wq * 4);
        float* dst = praw + (ri * 128 + c) * 33 + wq * 4;
        dst[0] = v.x; dst[1] = v.y; dst[2] = v.z; dst[3] = v.w;
    }
    __syncthreads();

    // ---------------- norms: norm2[ri][w] = sum_c p^2 ----------------
    if (tid < 384) {
        const int chalf = tid / 192;
        const int rw    = tid - chalf * 192;
        const int ri    = rw >> 5;
        const int w     = rw & 31;
        const float* src = praw + (ri * 128 + chalf * 64) * 33 + w;
        float s = 0.f;
        #pragma unroll 4
        for (int c = 0; c < 64; ++c) {
            const float v = src[c * 33];
            s = fmaf(v, v, s);
        }
        part[(chalf * 6 + ri) * 32 + w] = s;
    }
    __syncthreads();
    if (tid < 192) {
        const float n2 = part[tid] + part[192 + tid];
        invn[tid] = (n2 > 0.f) ? (1.0f / sqrtf(n2)) : 0.f;
    }
    __syncthreads();

    // ---------------- sim partials: thread = (cq, h, w) ----------------
    {
        const int cq = tid >> 7;
        const int h  = (tid >> 5) & 3;
        const int w  = tid & 31;
        const int wm = (w > 0)  ? w - 1 : 0;
        const int wp = (w < 31) ? w + 1 : 31;
        const float mL = (w > 0)  ? 1.f : 0.f;
        const float mR = (w < 31) ? 1.f : 0.f;
        float inv9[9];
        #pragma unroll
        for (int dh = 0; dh < 3; ++dh) {
            const float* ir = invn + (h + dh) * 32;
            inv9[dh * 3 + 0] = ir[wm] * mL;
            inv9[dh * 3 + 1] = ir[w];
            inv9[dh * 3 + 2] = ir[wp] * mR;
        }
        const float* b0 = praw + ((h + 0) * 128 + cq * 32) * 33;
        const float* b1 = b0 + 128 * 33;
        const float* b2 = b1 + 128 * 33;
        float acc = 0.f;
        #pragma unroll 4
        for (int i = 0; i < 32; ++i) {
            const float* r0p = b0 + i * 33;
            const float* r1p = b1 + i * 33;
            const float* r2p = b2 + i * 33;
            const float ctr = r1p[w];
            float box;
            box = r0p[wm] * inv9[0] + r0p[w] * inv9[1] + r0p[wp] * inv9[2];
            box = box + r1p[wm] * inv9[3] + ctr * inv9[4] + r1p[wp] * inv9[5];
            box = box + r2p[wm] * inv9[6] + r2p[w] * inv9[7] + r2p[wp] * inv9[8];
            acc = fmaf(ctr, box, acc);
        }
        spart[(cq * 4 + h) * 32 + w] = acc;
    }
    __syncthreads();
    if (tid < 128) {
        const int h = tid >> 5;
        const float s = spart[tid] + spart[128 + tid] + spart[256 + tid] + spart[384 + tid];
        simv[tid] = s * invn[(h + 1) * 32 + (tid & 31)] * (1.f / 9.f);
    }
    __syncthreads();

    // ---------------- output: lanes span channels for q-coalescing ----------------
    {
        const int lane = tid & 63;
        const int wv   = tid >> 6;  // 8 waves
        for (int pos = wv; pos < 128; pos += 8) {
            const int h = pos >> 5;
            const int w = pos & 31;
            const float sim = simv[pos];
            const size_t obase = (size_t)b * 131072 + (size_t)(r0 + h) * 2048 + (size_t)w * 64;
            #pragma unroll
            for (int chalf = 0; chalf < 2; ++chalf) {
                const int c = chalf * 64 + lane;
                const float val = praw[((h + 1) * 128 + c) * 33 + w] * sim;
                const int t = c & 1;
                const int q = c >> 1;
                out[obase + (size_t)t * 65536 + q] = val;
            }
        }
    }
}

extern "C" void kernel_launch(void* const* d_in, const int* in_sizes, int n_in,
                              void* d_out, int out_size, void* d_ws, size_t ws_size,
                              hipStream_t stream) {
    const float* p = (const float*)d_in[0];
    float* out = (float*)d_out;
    const size_t lds_bytes = (size_t)LDS_FLOATS * sizeof(float);  // 106,240 B
    (void)hipFuncSetAttribute((const void*)bcim_fused,
                              hipFuncAttributeMaxDynamicSharedMemorySize,
                              (int)lds_bytes);
    bcim_fused<<<dim3(2048), dim3(NTHR), lds_bytes, stream>>>(p, out);
    (void)in_sizes; (void)n_in; (void)out_size; (void)d_ws; (void)ws_size;
}

// Round 2
// 83.948 us; speedup vs baseline: 1.3692x; 1.3692x over previous
//
#include <hip/hip_runtime.h>

// sim[x] = (1/9) * inv[x] * sum_d inv[x+d] * S_d[x],  S_d[x] = sum_c p[c,x]*p[c,x+d]
// Channel dim is streamed (9 register accumulators per position) -> no big LDS retention.
// Phase 3 re-reads p (L3-warm) through a skewed LDS tile for the channel-transposed,
// q-coalesced output   out[b, c&1, h, w, c>>1] = p[b,c,h,w] * sim[b,h,w].

#define NTHR 256

__device__ __forceinline__ float dot4acc(float4 a, float4 b, float acc) {
    acc = fmaf(a.x, b.x, acc);
    acc = fmaf(a.y, b.y, acc);
    acc = fmaf(a.z, b.z, acc);
    acc = fmaf(a.w, b.w, acc);
    return acc;
}

__global__ __launch_bounds__(NTHR, 8) void bcim_v2(const float* __restrict__ p,
                                                   float* __restrict__ out) {
    __shared__ float regA[4224];      // phase1: [6 rows][32 w][12 c-pad] (2304 used); phase3: [128 pos][33]
    __shared__ float invL[6 * 32];    // inv-norm rows r0-1 .. r0+4 (0 for out-of-image)
    __shared__ float simv[128];       // sim for the strip's 4x32 positions

    const int tid = threadIdx.x;
    const int bid = blockIdx.x;
    const int b  = bid >> 3;
    const int r0 = (bid & 7) << 2;            // strip of 4 rows
    const float* __restrict__ pb = p + (size_t)b * 131072;   // 128*32*32

    // stencil roles: pairs of lanes split the 8-channel chunk
    const int chalf = tid & 1;
    const int pos   = tid >> 1;               // 0..127
    const int h     = pos >> 5;               // 0..3 (uniform per wave)
    const int w     = pos & 31;
    const int wm    = (w > 0) ? w - 1 : 0;    // clamped; masked later via inv
    const int wp    = (w < 31) ? w + 1 : 31;

    float s0=0.f,s1=0.f,s2=0.f,s3=0.f,s4=0.f,s5=0.f,s6=0.f,s7=0.f,s8=0.f;
    float hn = 0.f;                           // halo-row norm2 (top for h==0, bottom for h==3)

    // loader mapping: idx = k*256+tid -> wq=idx&7, c=(idx>>3)&7, r=idx>>6  (bank-spread, coalesced)
    const int l_wq = tid & 7;
    const int l_c  = (tid >> 3) & 7;
    const int l_r  = tid >> 6;                // 0..3 ; second pass covers rows 4..5

    // ---------------- phase 1: stream channels, accumulate S_d ----------------
    for (int ch = 0; ch < 16; ++ch) {
        const float* src = pb + (ch * 8 + l_c) * 1024 + l_wq * 4;
        {
            const int g = r0 - 1 + l_r;
            float4 v = make_float4(0.f, 0.f, 0.f, 0.f);
            if ((unsigned)g < 32u) v = *(const float4*)(src + g * 32);
            const int base = (l_r * 32 + l_wq * 4) * 12 + l_c;
            regA[base] = v.x; regA[base + 12] = v.y; regA[base + 24] = v.z; regA[base + 36] = v.w;
            if (tid < 128) {
                const int r2 = 4 + l_r;       // tid<128 -> l_r in {0,1} -> rows 4,5
                const int g2 = r0 - 1 + r2;
                float4 v2 = make_float4(0.f, 0.f, 0.f, 0.f);
                if ((unsigned)g2 < 32u) v2 = *(const float4*)(src + g2 * 32);
                const int base2 = (r2 * 32 + l_wq * 4) * 12 + l_c;
                regA[base2] = v2.x; regA[base2 + 12] = v2.y; regA[base2 + 24] = v2.z; regA[base2 + 36] = v2.w;
            }
        }
        __syncthreads();
        {
            const float4* sp = (const float4*)regA;   // quad idx = (r*32+w)*3 + chalf
            #define QK(r_, w_) sp[((r_) * 32 + (w_)) * 3 + chalf]
            float4 ctr = QK(h + 1, w);
            float4 a0 = QK(h, wm), a1 = QK(h, w), a2 = QK(h, wp);
            s0 = dot4acc(ctr, a0, s0);
            s1 = dot4acc(ctr, a1, s1);
            s2 = dot4acc(ctr, a2, s2);
            if (h == 0) hn = dot4acc(a1, a1, hn);
            float4 b0 = QK(h + 2, wm), b1 = QK(h + 2, w), b2 = QK(h + 2, wp);
            s6 = dot4acc(ctr, b0, s6);
            s7 = dot4acc(ctr, b1, s7);
            s8 = dot4acc(ctr, b2, s8);
            if (h == 3) hn = dot4acc(b1, b1, hn);
            float4 m0 = QK(h + 1, wm), m2 = QK(h + 1, wp);
            s3 = dot4acc(ctr, m0, s3);
            s4 = dot4acc(ctr, ctr, s4);
            s5 = dot4acc(ctr, m2, s5);
            #undef QK
        }
        __syncthreads();
    }

    // pair-reduce the channel halves (lanes 2k <-> 2k+1)
    s0 += __shfl_xor(s0, 1); s1 += __shfl_xor(s1, 1); s2 += __shfl_xor(s2, 1);
    s3 += __shfl_xor(s3, 1); s4 += __shfl_xor(s4, 1); s5 += __shfl_xor(s5, 1);
    s6 += __shfl_xor(s6, 1); s7 += __shfl_xor(s7, 1); s8 += __shfl_xor(s8, 1);
    hn += __shfl_xor(hn, 1);

    // ---------------- phase 2: inv-norms + sim ----------------
    if (chalf == 0) {
        const float invc = (s4 > 0.f) ? (1.0f / sqrtf(s4)) : 0.f;
        invL[(h + 1) * 32 + w] = invc;
        if (h == 0) invL[w]       = (hn > 0.f) ? (1.0f / sqrtf(hn)) : 0.f;
        if (h == 3) invL[160 + w] = (hn > 0.f) ? (1.0f / sqrtf(hn)) : 0.f;
    }
    __syncthreads();
    if (chalf == 0) {
        const float mL = (w > 0)  ? 1.f : 0.f;
        const float mR = (w < 31) ? 1.f : 0.f;
        const float* iT = invL + h * 32;
        const float* iM = iT + 32;
        const float* iB = iM + 32;
        float acc;
        acc = s0 * (iT[wm] * mL);
        acc = fmaf(s1, iT[w],        acc);
        acc = fmaf(s2, iT[wp] * mR,  acc);
        acc = fmaf(s3, iM[wm] * mL,  acc);
        acc = fmaf(s4, iM[w],        acc);
        acc = fmaf(s5, iM[wp] * mR,  acc);
        acc = fmaf(s6, iB[wm] * mL,  acc);
        acc = fmaf(s7, iB[w],        acc);
        acc = fmaf(s8, iB[wp] * mR,  acc);
        simv[pos] = acc * iM[w] * (1.0f / 9.0f);
    }
    __syncthreads();

    // ---------------- phase 3: transpose+scale output via skewed LDS tile ----------------
    // slab layout: [pos 0..127][33], column c'' = ((c&1)*16 + (c>>1 - qb) + 9*row) & 31
    for (int cb = 0; cb < 4; ++cb) {
        const int c0 = cb * 32;
        for (int st = 0; st < 4; ++st) {
            const int idx = st * 256 + tid;
            const int cl = idx >> 5;
            const int r  = (idx >> 3) & 3;
            const int wq = idx & 7;
            float4 v = *(const float4*)(pb + (c0 + cl) * 1024 + (r0 + r) * 32 + wq * 4);
            const int cp  = (cl & 1) * 16 + (cl >> 1);
            const int cpp = (cp + 9 * r) & 31;
            const int base = (r * 32 + wq * 4) * 33 + cpp;
            regA[base] = v.x; regA[base + 33] = v.y; regA[base + 66] = v.z; regA[base + 99] = v.w;
        }
        __syncthreads();
        const int qb = cb * 16;
        for (int st = 0; st < 4; ++st) {
            const int flat = st * 256 + tid;
            const int qf = flat & 3;
            const int t  = (flat >> 2) & 1;
            const int pp = flat >> 3;              // 0..127
            const int hh = pp >> 5;
            const int ww = pp & 31;
            const float sm = simv[pp];
            const int cb2 = t * 16 + qf * 4 + 9 * hh;
            const int a0 = pp * 33;
            float4 o;
            o.x = regA[a0 + ((cb2 + 0) & 31)] * sm;
            o.y = regA[a0 + ((cb2 + 1) & 31)] * sm;
            o.z = regA[a0 + ((cb2 + 2) & 31)] * sm;
            o.w = regA[a0 + ((cb2 + 3) & 31)] * sm;
            *(float4*)(out + (size_t)b * 131072 + (size_t)t * 65536 +
                       (size_t)(r0 + hh) * 2048 + ww * 64 + qb + qf * 4) = o;
        }
        __syncthreads();
    }
}

extern "C" void kernel_launch(void* const* d_in, const int* in_sizes, int n_in,
                              void* d_out, int out_size, void* d_ws, size_t ws_size,
                              hipStream_t stream) {
    const float* p = (const float*)d_in[0];
    float* out = (float*)d_out;
    bcim_v2<<<dim3(2048), dim3(NTHR), 0, stream>>>(p, out);
    (void)in_sizes; (void)n_in; (void)out_size; (void)d_ws; (void)ws_size;
}

// Round 3
// 82.376 us; speedup vs baseline: 1.3953x; 1.0191x over previous
//
#include <hip/hip_runtime.h>

// sim[x] = (1/9)*inv[x]*sum_d inv[x+d]*S_d[x],  S_d[x] = sum_c p[c,x]*p[c,x+d]
// v3: conflict-free XOR-swizzled phase-1 slab + T14 async-STAGE (issue-early /
// write-late) double buffering in registers for both the channel-stream phase
// and the output-transpose phase.

#define NTHR 256

__device__ __forceinline__ float dot4acc(float4 a, float4 b, float acc) {
    acc = fmaf(a.x, b.x, acc);
    acc = fmaf(a.y, b.y, acc);
    acc = fmaf(a.z, b.z, acc);
    acc = fmaf(a.w, b.w, acc);
    return acc;
}

__global__ __launch_bounds__(NTHR, 8) void bcim_v3(const float* __restrict__ p,
                                                   float* __restrict__ out) {
    __shared__ float slab[4224];   // phase1: [6][64 quads][4] = 1536 f; phase3: [128][33]
    __shared__ float invL[192];    // inv-norm rows r0-1..r0+4 (0 when out of image)
    __shared__ float simv[128];

    const int tid = threadIdx.x;
    const int b  = blockIdx.x >> 3;
    const int r0 = (blockIdx.x & 7) << 2;
    const float* __restrict__ pb = p + (size_t)b * 131072;  // 128*32*32

    // ---- phase-1 loader mapping: tid -> (wq, c, r); i1 covers rows 4,5 (tid<128)
    const int l_wq = tid & 7;
    const int l_c  = (tid >> 3) & 7;
    const int l_r  = tid >> 6;
    const int g0r  = r0 - 1 + l_r;
    const int g1r  = r0 + 3 + l_r;
    const bool in0 = ((unsigned)g0r < 32u);
    const bool in1 = (tid < 128) && ((unsigned)g1r < 32u);
    int wOff[4];
    {
        const int ch = l_c >> 2;
        const int ci = l_c & 3;
        #pragma unroll
        for (int j = 0; j < 4; ++j) {
            const int u = ((l_wq << 3) + (j << 1) + ch) ^ l_wq;   // swizzled quad
            wOff[j] = l_r * 256 + u * 4 + ci;
        }
    }
    const int gOff0 = l_c * 1024 + g0r * 32 + l_wq * 4;
    const int gOff1 = l_c * 1024 + g1r * 32 + l_wq * 4;

    // ---- stencil mapping: pairs of lanes split the 8-channel chunk
    const int chalf = tid & 1;
    const int pos   = tid >> 1;
    const int h     = pos >> 5;          // uniform per wave
    const int w     = pos & 31;
    const int wm    = (w > 0) ? w - 1 : 0;
    const int wp    = (w < 31) ? w + 1 : 31;
    const int uc    = (w  * 2 + chalf) ^ (w  >> 2);
    const int um    = (wm * 2 + chalf) ^ (wm >> 2);
    const int up    = (wp * 2 + chalf) ^ (wp >> 2);

    // ---- phase-3 mapping
    const int wq3 = tid & 7;
    const int r3  = (tid >> 3) & 3;
    const int clb = tid >> 5;
    const int p3g = clb * 1024 + (r0 + r3) * 32 + wq3 * 4;   // + cb*32768 + st*8192

    float4 st0 = make_float4(0.f, 0.f, 0.f, 0.f);
    float4 st1 = make_float4(0.f, 0.f, 0.f, 0.f);
    if (in0) st0 = *(const float4*)(pb + gOff0);
    if (in1) st1 = *(const float4*)(pb + gOff1);
    float4 q0, q1, q2, q3;

    float s0=0.f,s1=0.f,s2=0.f,s3=0.f,s4=0.f,s5=0.f,s6=0.f,s7=0.f,s8=0.f,hn=0.f;

    // ================= phase 1: stream channels =================
    for (int ch = 0; ch < 16; ++ch) {
        slab[wOff[0]] = st0.x; slab[wOff[1]] = st0.y;
        slab[wOff[2]] = st0.z; slab[wOff[3]] = st0.w;
        if (tid < 128) {
            slab[wOff[0] + 1024] = st1.x; slab[wOff[1] + 1024] = st1.y;
            slab[wOff[2] + 1024] = st1.z; slab[wOff[3] + 1024] = st1.w;
        }
        __syncthreads();
        if (ch < 15) {                       // issue next chunk's loads (latency hides under stencil)
            const int cbo = (ch + 1) << 13;  // *8192
            if (in0) st0 = *(const float4*)(pb + cbo + gOff0);
            if (in1) st1 = *(const float4*)(pb + cbo + gOff1);
        } else {                             // issue phase-3 cb0 loads (latency hides under phase 2)
            const float* base = pb + p3g;
            q0 = *(const float4*)(base);
            q1 = *(const float4*)(base + 8192);
            q2 = *(const float4*)(base + 16384);
            q3 = *(const float4*)(base + 24576);
        }
        {
            const float4* sp = (const float4*)slab;
            const float4 ctr = sp[(h + 1) * 64 + uc];
            float4 n0 = sp[h * 64 + um];
            float4 n1 = sp[h * 64 + uc];
            float4 n2 = sp[h * 64 + up];
            s0 = dot4acc(ctr, n0, s0);
            s1 = dot4acc(ctr, n1, s1);
            s2 = dot4acc(ctr, n2, s2);
            if (h == 0) hn = dot4acc(n1, n1, hn);
            n0 = sp[(h + 2) * 64 + um];
            n1 = sp[(h + 2) * 64 + uc];
            n2 = sp[(h + 2) * 64 + up];
            s6 = dot4acc(ctr, n0, s6);
            s7 = dot4acc(ctr, n1, s7);
            s8 = dot4acc(ctr, n2, s8);
            if (h == 3) hn = dot4acc(n1, n1, hn);
            n0 = sp[(h + 1) * 64 + um];
            n2 = sp[(h + 1) * 64 + up];
            s3 = dot4acc(ctr, n0, s3);
            s4 = dot4acc(ctr, ctr, s4);
            s5 = dot4acc(ctr, n2, s5);
        }
        __syncthreads();
    }

    // pair-reduce channel halves (lanes 2k <-> 2k+1)
    s0 += __shfl_xor(s0, 1); s1 += __shfl_xor(s1, 1); s2 += __shfl_xor(s2, 1);
    s3 += __shfl_xor(s3, 1); s4 += __shfl_xor(s4, 1); s5 += __shfl_xor(s5, 1);
    s6 += __shfl_xor(s6, 1); s7 += __shfl_xor(s7, 1); s8 += __shfl_xor(s8, 1);
    hn += __shfl_xor(hn, 1);

    // ================= phase 2: inv-norms + sim =================
    if (chalf == 0) {
        invL[(h + 1) * 32 + w] = (s4 > 0.f) ? (1.0f / sqrtf(s4)) : 0.f;
        if (h == 0) invL[w]       = (hn > 0.f) ? (1.0f / sqrtf(hn)) : 0.f;
        if (h == 3) invL[160 + w] = (hn > 0.f) ? (1.0f / sqrtf(hn)) : 0.f;
    }
    __syncthreads();
    if (chalf == 0) {
        const float mL = (w > 0)  ? 1.f : 0.f;
        const float mR = (w < 31) ? 1.f : 0.f;
        const float* iT = invL + h * 32;
        const float* iM = iT + 32;
        const float* iB = iM + 32;
        float acc;
        acc = s0 * (iT[wm] * mL);
        acc = fmaf(s1, iT[w],       acc);
        acc = fmaf(s2, iT[wp] * mR, acc);
        acc = fmaf(s3, iM[wm] * mL, acc);
        acc = fmaf(s4, iM[w],       acc);
        acc = fmaf(s5, iM[wp] * mR, acc);
        acc = fmaf(s6, iB[wm] * mL, acc);
        acc = fmaf(s7, iB[w],       acc);
        acc = fmaf(s8, iB[wp] * mR, acc);
        simv[pos] = acc * iM[w] * (1.0f / 9.0f);
    }
    __syncthreads();

    // ================= phase 3: transpose+scale output =================
    #pragma unroll
    for (int cb = 0; cb < 4; ++cb) {
        {   // write staged regs into skewed [128][33] tile
            int cl, cpp, basew;
            cl = clb;
            cpp = (((cl & 1) << 4) + (cl >> 1) + 9 * r3) & 31;
            basew = (r3 * 32 + wq3 * 4) * 33 + cpp;
            slab[basew] = q0.x; slab[basew+33] = q0.y; slab[basew+66] = q0.z; slab[basew+99] = q0.w;
            cl = 8 + clb;
            cpp = (((cl & 1) << 4) + (cl >> 1) + 9 * r3) & 31;
            basew = (r3 * 32 + wq3 * 4) * 33 + cpp;
            slab[basew] = q1.x; slab[basew+33] = q1.y; slab[basew+66] = q1.z; slab[basew+99] = q1.w;
            cl = 16 + clb;
            cpp = (((cl & 1) << 4) + (cl >> 1) + 9 * r3) & 31;
            basew = (r3 * 32 + wq3 * 4) * 33 + cpp;
            slab[basew] = q2.x; slab[basew+33] = q2.y; slab[basew+66] = q2.z; slab[basew+99] = q2.w;
            cl = 24 + clb;
            cpp = (((cl & 1) << 4) + (cl >> 1) + 9 * r3) & 31;
            basew = (r3 * 32 + wq3 * 4) * 33 + cpp;
            slab[basew] = q3.x; slab[basew+33] = q3.y; slab[basew+66] = q3.z; slab[basew+99] = q3.w;
        }
        __syncthreads();
        if (cb < 3) {                          // issue next cb's loads early
            const float* base = pb + ((cb + 1) << 15) + p3g;
            q0 = *(const float4*)(base);
            q1 = *(const float4*)(base + 8192);
            q2 = *(const float4*)(base + 16384);
            q3 = *(const float4*)(base + 24576);
        }
        const int qb = cb << 4;
        #pragma unroll
        for (int st = 0; st < 4; ++st) {
            const int flat = st * 256 + tid;
            const int qf = flat & 3;
            const int t  = (flat >> 2) & 1;
            const int pp = flat >> 3;
            const int hh = pp >> 5;
            const int ww = pp & 31;
            const float sm = simv[pp];
            const int cb2 = t * 16 + qf * 4 + 9 * hh;
            const int ai  = pp * 33;
            float4 o;
            o.x = slab[ai + ((cb2 + 0) & 31)] * sm;
            o.y = slab[ai + ((cb2 + 1) & 31)] * sm;
            o.z = slab[ai + ((cb2 + 2) & 31)] * sm;
            o.w = slab[ai + ((cb2 + 3) & 31)] * sm;
            *(float4*)(out + (size_t)b * 131072 + (size_t)t * 65536 +
                       (size_t)(r0 + hh) * 2048 + ww * 64 + qb + qf * 4) = o;
        }
        __syncthreads();
    }
}

extern "C" void kernel_launch(void* const* d_in, const int* in_sizes, int n_in,
                              void* d_out, int out_size, void* d_ws, size_t ws_size,
                              hipStream_t stream) {
    const float* p = (const float*)d_in[0];
    float* out = (float*)d_out;
    bcim_v3<<<dim3(2048), dim3(NTHR), 0, stream>>>(p, out);
    (void)in_sizes; (void)n_in; (void)out_size; (void)d_ws; (void)ws_size;
}